// Round 7
// baseline (185.558 us; speedup 1.0000x reference)
//
#include <hip/hip_runtime.h>
#include <math.h>

#define V 16384
#define D 256
#define NH 256
#define THREE_NH 768
#define IDIM 1024
#define LN_EPS 1e-12f
#define SCL 0.17677669529663687f

typedef short s16x8 __attribute__((ext_vector_type(8)));
typedef float f32x4 __attribute__((ext_vector_type(4)));

__device__ inline unsigned short f2bf(float f) {
    unsigned u = __float_as_uint(f);
    u += 0x7fffu + ((u >> 16) & 1u);          // RNE
    return (unsigned short)(u >> 16);
}
__device__ inline float bf2f(unsigned short s) {
    return __uint_as_float(((unsigned)s) << 16);
}

// Abramowitz-Stegun 7.1.26 erf, |err| < 1.5e-7 (invisible at bf16 tol)
__device__ inline float fast_erf(float x) {
    float ax = fabsf(x);
    float t  = 1.f / fmaf(0.3275911f, ax, 1.f);
    float p  = fmaf(fmaf(fmaf(fmaf(1.061405429f, t, -1.453152027f), t,
                              1.421413741f), t, -0.284496736f), t, 0.254829592f);
    float e  = 1.f - p * t * __expf(-ax * ax);
    return copysignf(e, x);
}

// async global->LDS, 16B per lane. LDS dest = wave-uniform base + lane*16.
__device__ inline void gl2lds16(const unsigned short* g, unsigned short* l) {
    __builtin_amdgcn_global_load_lds(
        (__attribute__((address_space(1))) void*)(g),
        (__attribute__((address_space(3))) void*)(l), 16, 0, 0);
}

// Stage ROWS_T x 64 bf16 tile (row-major, leading dim ldk) into LDS.
// 16B chunk c of row r stored at chunk slot c ^ (r&7).
template <int ROWS_T>
__device__ inline void stage(const unsigned short* __restrict__ src, size_t row0,
                             int ldk, int k0, unsigned short* lds, int wv, int lane) {
    constexpr int PER_WAVE = ROWS_T / 32;     // 1KB segments per wave
    #pragma unroll
    for (int i = 0; i < PER_WAVE; ++i) {
        const int seg = wv * PER_WAVE + i;
        const int r = seg * 8 + (lane >> 3);
        const int c = (lane & 7) ^ (r & 7);
        gl2lds16(src + (row0 + (size_t)r) * ldk + k0 + c * 8, lds + seg * 512);
    }
}

// read one 8-elem bf16 fragment (16B) for (row, chunk) from swizzled tile
__device__ inline s16x8 fragld(const unsigned short* lds, int row, int chunk) {
    return *(const s16x8*)&lds[row * 64 + ((chunk ^ (row & 7)) << 3)];
}

// ---------------------------------------------------------------------------
// prep: one launch for all conversions.
// ---------------------------------------------------------------------------
__global__ __launch_bounds__(256) void prep(const float* __restrict__ X,
                                            unsigned short* __restrict__ Xb,
                                            const float* __restrict__ Wqkv,
                                            const float* __restrict__ Wo,
                                            const float* __restrict__ Wi,
                                            const float* __restrict__ Wo2,
                                            unsigned short* __restrict__ WqkvT,
                                            unsigned short* __restrict__ WoT,
                                            unsigned short* __restrict__ WiT,
                                            unsigned short* __restrict__ Wo2T) {
    const int b = blockIdx.x, t = threadIdx.x;
    if (b >= 768) {
        int i = (b - 768) * 256 + t;
        float4 v = ((const float4*)X)[i];
        ushort4 o;
        o.x = f2bf(v.x); o.y = f2bf(v.y); o.z = f2bf(v.z); o.w = f2bf(v.w);
        ((ushort4*)Xb)[i] = o;
        return;
    }
    __shared__ float tile[32][33];
    const float* W; unsigned short* Wt; int K, N, bx, by;
    if (b < 192)      { W = Wqkv; Wt = WqkvT; K = 256;  N = 768;  bx = b & 7;          by = b >> 3; }
    else if (b < 256) { W = Wo;   Wt = WoT;   K = 256;  N = 256;  bx = (b - 192) & 7;  by = (b - 192) >> 3; }
    else if (b < 512) { W = Wi;   Wt = WiT;   K = 256;  N = 1024; bx = (b - 256) & 7;  by = (b - 256) >> 3; }
    else              { W = Wo2;  Wt = Wo2T;  K = 1024; N = 256;  bx = (b - 512) & 31; by = (b - 512) >> 5; }
    const int k0 = bx * 32, n0 = by * 32;
    #pragma unroll
    for (int p = 0; p < 4; ++p) {
        int idx = t + p * 256, r = idx >> 5, c = idx & 31;
        tile[r][c] = W[(size_t)(k0 + r) * N + n0 + c];
    }
    __syncthreads();
    #pragma unroll
    for (int p = 0; p < 4; ++p) {
        int idx = t + p * 256, r = idx >> 5, c = idx & 31;
        Wt[(size_t)(n0 + r) * K + k0 + c] = f2bf(tile[c][r]);
    }
}

// ---------------------------------------------------------------------------
// gemm128<K,N,EPI>: C = A @ Bt^T.  128x128 tile, BK=64, single-buffered,
// XCD row-band swizzle (R2-verified structure; B tile HAS 2-way cross-wave
// reuse here, so LDS staging stays).
// ---------------------------------------------------------------------------
template <int K, int N, int EPI>
__global__ __launch_bounds__(256) void gemm128(const unsigned short* __restrict__ A,
                                               const unsigned short* __restrict__ Bt,
                                               unsigned short* __restrict__ C) {
    __shared__ unsigned short As[128 * 64];
    __shared__ unsigned short Bs[128 * 64];
    constexpr int NCOL = N / 128;
    const int b = blockIdx.x;
    const int idx = b >> 3;
    const int r0 = ((b & 7) * 16 + idx / NCOL) * 128;
    const int c0 = (idx % NCOL) * 128;
    const int t = threadIdx.x;
    const int wv = t >> 6, lane = t & 63, q = lane >> 4, l16 = lane & 15;
    const int wr = (wv >> 1) * 64, wc = (wv & 1) * 64;
    f32x4 acc[4][4] = {};

    for (int k0 = 0; k0 < K; k0 += 64) {
        __syncthreads();
        stage<128>(A,  (size_t)r0, K, k0, As, wv, lane);
        stage<128>(Bt, (size_t)c0, K, k0, Bs, wv, lane);
        __builtin_amdgcn_s_waitcnt(0);
        __syncthreads();
        #pragma unroll
        for (int kk2 = 0; kk2 < 2; ++kk2) {
            s16x8 af[4], bfr[4];
            #pragma unroll
            for (int mf = 0; mf < 4; ++mf)
                af[mf] = fragld(As, wr + mf * 16 + l16, kk2 * 4 + q);
            #pragma unroll
            for (int nf = 0; nf < 4; ++nf)
                bfr[nf] = fragld(Bs, wc + nf * 16 + l16, kk2 * 4 + q);
            #pragma unroll
            for (int mf = 0; mf < 4; ++mf)
                #pragma unroll
                for (int nf = 0; nf < 4; ++nf)
                    acc[mf][nf] = __builtin_amdgcn_mfma_f32_16x16x32_bf16(af[mf], bfr[nf], acc[mf][nf], 0, 0, 0);
        }
    }

    #pragma unroll
    for (int mf = 0; mf < 4; ++mf)
        #pragma unroll
        for (int nf = 0; nf < 4; ++nf) {
            const int cg = c0 + wc + nf * 16 + l16;
            #pragma unroll
            for (int r = 0; r < 4; ++r) {
                const int rg = r0 + wr + mf * 16 + q * 4 + r;
                float v = acc[mf][nf][r];
                if (EPI == 1) v = 0.5f * v * (1.f + fast_erf(v * 0.70710678118654752f));
                C[(size_t)rg * N + cg] = f2bf(v);
            }
        }
}

// ---------------------------------------------------------------------------
// ffn_ln: out = LN( gelu(pre @ WiT^T) @ Wo2T^T + pre ), fp32 out.
// FUSED FFN, DIRECT-B: wave wv only ever consumed Bs rows wc..wc+63 = the
// rows it staged itself (zero cross-wave reuse), so B staging was a pure
// round-trip + 32x (vmcnt(0) drain + 2 barriers).  Both GEMMs now read
// B-fragments directly from global (L2-resident weights, coalesced
// 16rows x 64B per wave-instruction); K-loops are barrier-free and the
// compiler pipelines the L2 loads under MFMA.
// Per block (BM=32, 512 blocks, 33.3 KB LDS):
//   Apre staged once (16 KB, fragld layout) — GEMM1 A + residual.
//   for nc in 0..3: GEMM1(direct B) -> gelu -> Pbuf -> barrier ->
//                   GEMM2(direct B, acc2 +=) -> barrier.
//   epilogue: acc2 + residual(from Apre LDS), fused row-LN.
// ---------------------------------------------------------------------------
__global__ __launch_bounds__(256) void ffn_ln(const unsigned short* __restrict__ preb,
                                              const unsigned short* __restrict__ WiT,
                                              const unsigned short* __restrict__ Wo2T,
                                              const float* __restrict__ gamma,
                                              const float* __restrict__ beta,
                                              float* __restrict__ out) {
    __shared__ unsigned short Apre[32 * 64 * 4];   // 16 KB: 4 fragld k-chunk tiles
    __shared__ unsigned short Pbuf[32 * 64 * 4];   // 16 KB: inter chunk, 4 k-sub tiles
    __shared__ float2 partial[4][32];
    __shared__ float2 stats[32];
    const int t = threadIdx.x, r0 = blockIdx.x * 32;
    const int wv = t >> 6, lane = t & 63, q = lane >> 4, l16 = lane & 15;
    const int wc = wv * 64;
    f32x4 acc2[2][4] = {};

    // stage A (preb rows, full K=256) once
    #pragma unroll
    for (int kc = 0; kc < 4; ++kc)
        stage<32>(preb, (size_t)r0, 256, kc * 64, Apre + kc * 2048, wv, lane);
    __builtin_amdgcn_s_waitcnt(0);
    __syncthreads();

    const unsigned short* Bp2 = Wo2T + (size_t)(wc + l16) * IDIM;

    for (int nc = 0; nc < 4; ++nc) {
        // ---- GEMM1: inter chunk [32 x 256], direct-B, barrier-free ----
        const unsigned short* Bp1 = WiT + (size_t)(nc * 256 + wc + l16) * 256;
        f32x4 acc1[2][4] = {};
        #pragma unroll
        for (int k0 = 0; k0 < 256; k0 += 64) {
            const unsigned short* Ak = Apre + (k0 >> 6) * 2048;
            #pragma unroll
            for (int kk2 = 0; kk2 < 2; ++kk2) {
                s16x8 af[2], bv[4];
                #pragma unroll
                for (int mf = 0; mf < 2; ++mf)
                    af[mf] = fragld(Ak, mf * 16 + l16, kk2 * 4 + q);
                #pragma unroll
                for (int nf = 0; nf < 4; ++nf)
                    bv[nf] = *(const s16x8*)&Bp1[(size_t)nf * 16 * 256 + k0 + (kk2 * 4 + q) * 8];
                #pragma unroll
                for (int mf = 0; mf < 2; ++mf)
                    #pragma unroll
                    for (int nf = 0; nf < 4; ++nf)
                        acc1[mf][nf] = __builtin_amdgcn_mfma_f32_16x16x32_bf16(af[mf], bv[nf], acc1[mf][nf], 0, 0, 0);
            }
        }

        // ---- gelu -> Pbuf (fragld layout; wave wv owns tile wv) ----
        // (prev GEMM2 finished reading Pbuf: barrier at end of prev iteration)
        #pragma unroll
        for (int mf = 0; mf < 2; ++mf)
            #pragma unroll
            for (int nf = 0; nf < 4; ++nf)
                #pragma unroll
                for (int r = 0; r < 4; ++r) {
                    float v = acc1[mf][nf][r];
                    v = 0.5f * v * (1.f + fast_erf(v * 0.70710678118654752f));
                    const int i = mf * 16 + q * 4 + r;          // row 0..31
                    const int colc = wc + nf * 16 + l16;        // col in chunk 0..255
                    const int c8 = (colc >> 3) & 7;
                    Pbuf[wv * 2048 + i * 64 + ((c8 ^ (i & 7)) << 3) + (colc & 7)] = f2bf(v);
                }
        __syncthreads();   // Pbuf visible to all waves

        // ---- GEMM2: acc2 += inter_chunk @ Wo2T k-slice, direct-B ----
        #pragma unroll
        for (int ks = 0; ks < 256; ks += 64) {
            const unsigned short* Pk = Pbuf + (ks >> 6) * 2048;
            #pragma unroll
            for (int kk2 = 0; kk2 < 2; ++kk2) {
                s16x8 af[2], bv[4];
                #pragma unroll
                for (int mf = 0; mf < 2; ++mf)
                    af[mf] = fragld(Pk, mf * 16 + l16, kk2 * 4 + q);
                #pragma unroll
                for (int nf = 0; nf < 4; ++nf)
                    bv[nf] = *(const s16x8*)&Bp2[(size_t)nf * 16 * IDIM + nc * 256 + ks + (kk2 * 4 + q) * 8];
                #pragma unroll
                for (int mf = 0; mf < 2; ++mf)
                    #pragma unroll
                    for (int nf = 0; nf < 4; ++nf)
                        acc2[mf][nf] = __builtin_amdgcn_mfma_f32_16x16x32_bf16(af[mf], bv[nf], acc2[mf][nf], 0, 0, 0);
            }
        }
        __syncthreads();   // Pbuf reads done before next nc's gelu overwrites
    }

    // ---- + residual (from Apre LDS, not global) ----
    #pragma unroll
    for (int mf = 0; mf < 2; ++mf)
        #pragma unroll
        for (int nf = 0; nf < 4; ++nf) {
            const int cg = wc + nf * 16 + l16;
            const int kb = cg >> 6, c8 = (cg >> 3) & 7, e = cg & 7;
            #pragma unroll
            for (int r = 0; r < 4; ++r) {
                const int i = mf * 16 + q * 4 + r;
                acc2[mf][nf][r] += bf2f(Apre[kb * 2048 + i * 64 + ((c8 ^ (i & 7)) << 3) + e]);
            }
        }

    // ---- fused row LN ----
    #pragma unroll
    for (int mf = 0; mf < 2; ++mf) {
        float s[4] = {0.f, 0.f, 0.f, 0.f}, ss[4] = {0.f, 0.f, 0.f, 0.f};
        #pragma unroll
        for (int nf = 0; nf < 4; ++nf)
            #pragma unroll
            for (int r = 0; r < 4; ++r) {
                float v = acc2[mf][nf][r];
                s[r] += v; ss[r] += v * v;
            }
        #pragma unroll
        for (int off = 1; off < 16; off <<= 1)
            #pragma unroll
            for (int r = 0; r < 4; ++r) {
                s[r]  += __shfl_xor(s[r],  off);
                ss[r] += __shfl_xor(ss[r], off);
            }
        if (l16 == 0)
            #pragma unroll
            for (int r = 0; r < 4; ++r)
                partial[wv][mf * 16 + q * 4 + r] = make_float2(s[r], ss[r]);
    }
    __syncthreads();
    if (t < 32) {
        float s = 0.f, ss = 0.f;
        #pragma unroll
        for (int w = 0; w < 4; ++w) { s += partial[w][t].x; ss += partial[w][t].y; }
        float mu  = s * (1.f / 256.f);
        float var = ss * (1.f / 256.f) - mu * mu;
        stats[t] = make_float2(mu, rsqrtf(var + LN_EPS));
    }
    __syncthreads();

    #pragma unroll
    for (int mf = 0; mf < 2; ++mf)
        #pragma unroll
        for (int nf = 0; nf < 4; ++nf) {
            const int cg = wc + nf * 16 + l16;
            const float g = gamma[cg], b = beta[cg];
            #pragma unroll
            for (int r = 0; r < 4; ++r) {
                const int rl = mf * 16 + q * 4 + r;
                const float2 st = stats[rl];
                out[(size_t)(r0 + rl) * NH + cg] = (acc2[mf][nf][r] - st.x) * st.y * g + b;
            }
        }
}

// ---------------------------------------------------------------------------
// FUSED attention + W_o GEMM + LN1 — MFMA phase A (R5-verified).
// Phase B now DIRECT-B (WoT, zero cross-wave reuse of the old Bs staging):
// barrier-free K-loop, 4 stage rounds / 8 barriers removed.
// ---------------------------------------------------------------------------
__global__ __launch_bounds__(256) void attln(const unsigned short* __restrict__ qkv,
                                             const unsigned short* __restrict__ WoT,
                                             const float* __restrict__ X,
                                             const float* __restrict__ gamma,
                                             const float* __restrict__ beta,
                                             unsigned short* __restrict__ preb) {
    __shared__ unsigned short smem[25216];
    unsigned short* Ks = smem;                 // [0, 8192): h*1024 + j*32 + c*8
    unsigned short* Vt = smem + 8192;          // [8192,16384): h*1024 + d*32 + swz
    unsigned short* Ps = smem + 16384;         // [16384,24576): h*1024 + row*32 + swz
    unsigned short* at = smem;                 // phase B A-tile (overlays Ks)
    float2* partial = (float2*)(smem + 24576);
    float2* stats   = (float2*)(smem + 24576 + 512);

    const int g = blockIdx.x, t = threadIdx.x;
    const int wv = t >> 6, lane = t & 63, q = lane >> 4, l16 = lane & 15;
    const unsigned short* src = qkv + (size_t)g * 32 * THREE_NH;

    // ---- Q fragments direct from global ----
    s16x8 qf[2][2];
    #pragma unroll
    for (int hh = 0; hh < 2; ++hh)
        #pragma unroll
        for (int mf = 0; mf < 2; ++mf)
            qf[hh][mf] = *(const s16x8*)&src[(size_t)(mf * 16 + l16) * THREE_NH +
                                             (wv * 2 + hh) * 96 + q * 8];

    // ---- V 16B chunks to regs ----
    s16x8 vld[4];
    int vh[4], vj[4], vdc[4];
    #pragma unroll
    for (int i = 0; i < 4; ++i) {
        int cid = i * 256 + t;
        vh[i] = cid >> 7; int rem = cid & 127; vj[i] = rem >> 2; vdc[i] = rem & 3;
        vld[i] = *(const s16x8*)&src[(size_t)vj[i] * THREE_NH + vh[i] * 96 + 64 + vdc[i] * 8];
    }

    // ---- K async global->LDS ----
    #pragma unroll
    for (int i = 0; i < 4; ++i) {
        int ck = (wv * 4 + i) * 64 + lane;
        int h = ck >> 7, j = (ck >> 2) & 31, c = ck & 3;
        gl2lds16(src + (size_t)j * THREE_NH + h * 96 + 32 + c * 8, Ks + (wv * 4 + i) * 512);
    }

    // ---- Vt scatter: Vt[h][d][j], chunk slot (j>>3) ^ ((d>>2)&3) ----
    #pragma unroll
    for (int i = 0; i < 4; ++i)
        #pragma unroll
        for (int e = 0; e < 8; ++e) {
            int d = vdc[i] * 8 + e;
            Vt[vh[i] * 1024 + d * 32 + ((((vj[i] >> 3) ^ ((d >> 2) & 3))) << 3) + (vj[i] & 7)] =
                (unsigned short)vld[i][e];
        }

    __builtin_amdgcn_s_waitcnt(0);
    __syncthreads();

    // ---- scores: S[h] = Q @ K^T ----
    f32x4 sacc[2][2][2] = {};
    #pragma unroll
    for (int hh = 0; hh < 2; ++hh) {
        const int h = wv * 2 + hh;
        #pragma unroll
        for (int nf = 0; nf < 2; ++nf) {
            s16x8 kf = *(const s16x8*)&Ks[h * 1024 + (nf * 16 + l16) * 32 + q * 8];
            #pragma unroll
            for (int mf = 0; mf < 2; ++mf)
                sacc[hh][mf][nf] = __builtin_amdgcn_mfma_f32_16x16x32_bf16(
                    qf[hh][mf], kf, sacc[hh][mf][nf], 0, 0, 0);
        }
    }

    // ---- softmax (C-layout rows), deferred denominator ----
    float inv[2][2][4];
    #pragma unroll
    for (int hh = 0; hh < 2; ++hh) {
        const int h = wv * 2 + hh;
        #pragma unroll
        for (int mf = 0; mf < 2; ++mf)
            #pragma unroll
            for (int r = 0; r < 4; ++r) {
                float a0 = sacc[hh][mf][0][r], a1 = sacc[hh][mf][1][r];
                float m = fmaxf(a0, a1);
                m = fmaxf(m, __shfl_xor(m, 1));
                m = fmaxf(m, __shfl_xor(m, 2));
                m = fmaxf(m, __shfl_xor(m, 4));
                m = fmaxf(m, __shfl_xor(m, 8));
                float e0 = __expf((a0 - m) * SCL);
                float e1 = __expf((a1 - m) * SCL);
                float sm = e0 + e1;
                sm += __shfl_xor(sm, 1);
                sm += __shfl_xor(sm, 2);
                sm += __shfl_xor(sm, 4);
                sm += __shfl_xor(sm, 8);
                inv[hh][mf][r] = 1.f / sm;
                const int row = mf * 16 + q * 4 + r;
                const int base = h * 1024 + row * 32 + (l16 & 7);
                Ps[base + ((((l16 >> 3) ^ q)) << 3)]       = f2bf(e0);
                Ps[base + ((((2 + (l16 >> 3)) ^ q)) << 3)] = f2bf(e1);
            }
    }

    // ---- PV ----
    f32x4 oacc[2][2][2] = {};
    #pragma unroll
    for (int hh = 0; hh < 2; ++hh) {
        const int h = wv * 2 + hh;
        const int sw = (l16 >> 2) & 3;
        s16x8 pa[2], vb[2];
        #pragma unroll
        for (int mf = 0; mf < 2; ++mf)
            pa[mf] = *(const s16x8*)&Ps[h * 1024 + (mf * 16 + l16) * 32 + ((q ^ sw) << 3)];
        #pragma unroll
        for (int nf = 0; nf < 2; ++nf)
            vb[nf] = *(const s16x8*)&Vt[h * 1024 + (nf * 16 + l16) * 32 + ((q ^ sw) << 3)];
        #pragma unroll
        for (int mf = 0; mf < 2; ++mf)
            #pragma unroll
            for (int nf = 0; nf < 2; ++nf)
                oacc[hh][mf][nf] = __builtin_amdgcn_mfma_f32_16x16x32_bf16(
                    pa[mf], vb[nf], oacc[hh][mf][nf], 0, 0, 0);
    }
    __syncthreads();

    // ---- bridge: O * inv -> at (fragld layout) ----
    #pragma unroll
    for (int hh = 0; hh < 2; ++hh)
        #pragma unroll
        for (int mf = 0; mf < 2; ++mf)
            #pragma unroll
            for (int nf = 0; nf < 2; ++nf)
                #pragma unroll
                for (int r = 0; r < 4; ++r) {
                    float val = oacc[hh][mf][nf][r] * inv[hh][mf][r];
                    const int i = mf * 16 + q * 4 + r;
                    const int col = (wv * 2 + hh) * 32 + nf * 16 + l16;
                    const int kb = col >> 6, c = (col >> 3) & 7;
                    at[kb * 2048 + i * 64 + ((c ^ (i & 7)) << 3) + (col & 7)] = f2bf(val);
                }
    __syncthreads();   // at visible to all waves

    // ---- phase B: pre = LN(at @ WoT^T + X), direct-B, barrier-free ----
    const int wc = wv * 64;
    const int r0 = g * 32;
    f32x4 acc[2][4] = {};
    const unsigned short* Bp = WoT + (size_t)(wc + l16) * NH;

    #pragma unroll
    for (int kc = 0; kc < 4; ++kc) {
        const unsigned short* atk = at + kc * 2048;
        #pragma unroll
        for (int kk2 = 0; kk2 < 2; ++kk2) {
            s16x8 af[2], bv[4];
            #pragma unroll
            for (int mf = 0; mf < 2; ++mf)
                af[mf] = fragld(atk, mf * 16 + l16, kk2 * 4 + q);
            #pragma unroll
            for (int nf = 0; nf < 4; ++nf)
                bv[nf] = *(const s16x8*)&Bp[(size_t)nf * 16 * NH + kc * 64 + (kk2 * 4 + q) * 8];
            #pragma unroll
            for (int mf = 0; mf < 2; ++mf)
                #pragma unroll
                for (int nf = 0; nf < 4; ++nf)
                    acc[mf][nf] = __builtin_amdgcn_mfma_f32_16x16x32_bf16(af[mf], bv[nf], acc[mf][nf], 0, 0, 0);
        }
    }

    #pragma unroll
    for (int mf = 0; mf < 2; ++mf)
        #pragma unroll
        for (int nf = 0; nf < 4; ++nf) {
            const int cg = wc + nf * 16 + l16;
            #pragma unroll
            for (int r = 0; r < 4; ++r)
                acc[mf][nf][r] += X[(size_t)(r0 + mf * 16 + q * 4 + r) * NH + cg];
        }

    #pragma unroll
    for (int mf = 0; mf < 2; ++mf) {
        float sp[4] = {0.f, 0.f, 0.f, 0.f}, ssp[4] = {0.f, 0.f, 0.f, 0.f};
        #pragma unroll
        for (int nf = 0; nf < 4; ++nf)
            #pragma unroll
            for (int r = 0; r < 4; ++r) {
                float v = acc[mf][nf][r];
                sp[r] += v; ssp[r] += v * v;
            }
        #pragma unroll
        for (int off = 1; off < 16; off <<= 1)
            #pragma unroll
            for (int r = 0; r < 4; ++r) {
                sp[r]  += __shfl_xor(sp[r],  off);
                ssp[r] += __shfl_xor(ssp[r], off);
            }
        if (l16 == 0)
            #pragma unroll
            for (int r = 0; r < 4; ++r)
                partial[wv * 32 + mf * 16 + q * 4 + r] = make_float2(sp[r], ssp[r]);
    }
    __syncthreads();
    if (t < 32) {
        float sv = 0.f, ssv = 0.f;
        #pragma unroll
        for (int w = 0; w < 4; ++w) { sv += partial[w * 32 + t].x; ssv += partial[w * 32 + t].y; }
        float mu  = sv * (1.f / 256.f);
        float var = ssv * (1.f / 256.f) - mu * mu;
        stats[t] = make_float2(mu, rsqrtf(var + LN_EPS));
    }
    __syncthreads();

    #pragma unroll
    for (int mf = 0; mf < 2; ++mf)
        #pragma unroll
        for (int nf = 0; nf < 4; ++nf) {
            const int cg = wc + nf * 16 + l16;
            const float gm = gamma[cg], bt = beta[cg];
            #pragma unroll
            for (int r = 0; r < 4; ++r) {
                const int rl = mf * 16 + q * 4 + r;
                const float2 st = stats[rl];
                float v = (acc[mf][nf][r] - st.x) * st.y * gm + bt;
                preb[(size_t)(r0 + rl) * NH + cg] = f2bf(v);
            }
        }
}

// ---------------------------------------------------------------------------
extern "C" void kernel_launch(void* const* d_in, const int* in_sizes, int n_in,
                              void* d_out, int out_size, void* d_ws, size_t ws_size,
                              hipStream_t stream) {
    const float* X      = (const float*)d_in[0];
    const float* W_qkv  = (const float*)d_in[2];
    const float* W_o    = (const float*)d_in[3];
    const float* ln1_g  = (const float*)d_in[4];
    const float* ln1_b  = (const float*)d_in[5];
    const float* W_i    = (const float*)d_in[6];
    const float* W_out2 = (const float*)d_in[7];
    const float* ln2_g  = (const float*)d_in[8];
    const float* ln2_b  = (const float*)d_in[9];
    float* out = (float*)d_out;

    char* ws = (char*)d_ws;
    unsigned short* Xbf   = (unsigned short*)(ws);                 //  8.0 MB
    unsigned short* qkvb  = (unsigned short*)(ws + 8388608);       // 25.2 MB
    unsigned short* preb  = (unsigned short*)(ws + 58720256);      //  8.0 MB
    unsigned short* WqkvT = (unsigned short*)(ws + 67108864);
    unsigned short* WoT   = (unsigned short*)(ws + 67502080);
    unsigned short* WiT   = (unsigned short*)(ws + 67633152);
    unsigned short* Wo2T  = (unsigned short*)(ws + 68157440);

    dim3 blk(256);
    hipLaunchKernelGGL(prep, dim3(768 + V * D / 4 / 256), blk, 0, stream,
                       X, Xbf, W_qkv, W_o, W_i, W_out2, WqkvT, WoT, WiT, Wo2T);

    hipLaunchKernelGGL((gemm128<D, THREE_NH, 0>), dim3(V / 128 * (THREE_NH / 128)), blk, 0, stream,
                       Xbf, WqkvT, qkvb);
    hipLaunchKernelGGL(attln, dim3(V / 32), blk, 0, stream,
                       qkvb, WoT, X, ln1_g, ln1_b, preb);
    hipLaunchKernelGGL(ffn_ln, dim3(V / 32), blk, 0, stream,
                       preb, WiT, Wo2T, ln2_g, ln2_b, out);
}

// Round 8
// 153.656 us; speedup vs baseline: 1.2076x; 1.2076x over previous
//
#include <hip/hip_runtime.h>
#include <math.h>

#define V 16384
#define D 256
#define NH 256
#define THREE_NH 768
#define IDIM 1024
#define LN_EPS 1e-12f
#define SCL 0.17677669529663687f

typedef short s16x8 __attribute__((ext_vector_type(8)));
typedef float f32x4 __attribute__((ext_vector_type(4)));

__device__ inline unsigned short f2bf(float f) {
    unsigned u = __float_as_uint(f);
    u += 0x7fffu + ((u >> 16) & 1u);          // RNE
    return (unsigned short)(u >> 16);
}
__device__ inline float bf2f(unsigned short s) {
    return __uint_as_float(((unsigned)s) << 16);
}

// Abramowitz-Stegun 7.1.26 erf, |err| < 1.5e-7 (invisible at bf16 tol)
__device__ inline float fast_erf(float x) {
    float ax = fabsf(x);
    float t  = 1.f / fmaf(0.3275911f, ax, 1.f);
    float p  = fmaf(fmaf(fmaf(fmaf(1.061405429f, t, -1.453152027f), t,
                              1.421413741f), t, -0.284496736f), t, 0.254829592f);
    float e  = 1.f - p * t * __expf(-ax * ax);
    return copysignf(e, x);
}

// async global->LDS, 16B per lane. LDS dest = wave-uniform base + lane*16.
__device__ inline void gl2lds16(const unsigned short* g, unsigned short* l) {
    __builtin_amdgcn_global_load_lds(
        (__attribute__((address_space(1))) void*)(g),
        (__attribute__((address_space(3))) void*)(l), 16, 0, 0);
}

// Cooperative stage: ROWS_T x 64 bf16 tile, all 4 waves, fragld layout.
template <int ROWS_T>
__device__ inline void stage(const unsigned short* __restrict__ src, size_t row0,
                             int ldk, int k0, unsigned short* lds, int wv, int lane) {
    constexpr int PER_WAVE = ROWS_T / 32;     // 1KB segments per wave
    #pragma unroll
    for (int i = 0; i < PER_WAVE; ++i) {
        const int seg = wv * PER_WAVE + i;
        const int r = seg * 8 + (lane >> 3);
        const int c = (lane & 7) ^ (r & 7);
        gl2lds16(src + (row0 + (size_t)r) * ldk + k0 + c * 8, lds + seg * 512);
    }
}

// WAVE-PRIVATE stage: one wave stages its own 64x64 tile (8KB segment),
// fragld-compatible layout, synced by wave-local vmcnt only (no barriers).
__device__ inline void stage_wp(const unsigned short* __restrict__ src, size_t row0,
                                int ldk, int k0, unsigned short* seg, int lane) {
    #pragma unroll
    for (int i = 0; i < 8; ++i) {
        const int r = i * 8 + (lane >> 3);
        const int c = (lane & 7) ^ (r & 7);
        gl2lds16(src + (row0 + (size_t)r) * ldk + k0 + c * 8, seg + i * 512);
    }
}

// read one 8-elem bf16 fragment (16B) for (row, chunk) from swizzled tile
__device__ inline s16x8 fragld(const unsigned short* lds, int row, int chunk) {
    return *(const s16x8*)&lds[row * 64 + ((chunk ^ (row & 7)) << 3)];
}

// per-wave round preamble/wait (rule #18: pin with sched_barrier)
#define WAVE_LGKM0() do { asm volatile("s_waitcnt lgkmcnt(0)" ::: "memory"); \
                          __builtin_amdgcn_sched_barrier(0); } while (0)
#define WAVE_VM0()   do { asm volatile("s_waitcnt vmcnt(0)" ::: "memory");   \
                          __builtin_amdgcn_sched_barrier(0); } while (0)

// ---------------------------------------------------------------------------
// prep: one launch for all conversions.
// ---------------------------------------------------------------------------
__global__ __launch_bounds__(256) void prep(const float* __restrict__ X,
                                            unsigned short* __restrict__ Xb,
                                            const float* __restrict__ Wqkv,
                                            const float* __restrict__ Wo,
                                            const float* __restrict__ Wi,
                                            const float* __restrict__ Wo2,
                                            unsigned short* __restrict__ WqkvT,
                                            unsigned short* __restrict__ WoT,
                                            unsigned short* __restrict__ WiT,
                                            unsigned short* __restrict__ Wo2T) {
    const int b = blockIdx.x, t = threadIdx.x;
    if (b >= 768) {
        int i = (b - 768) * 256 + t;
        float4 v = ((const float4*)X)[i];
        ushort4 o;
        o.x = f2bf(v.x); o.y = f2bf(v.y); o.z = f2bf(v.z); o.w = f2bf(v.w);
        ((ushort4*)Xb)[i] = o;
        return;
    }
    __shared__ float tile[32][33];
    const float* W; unsigned short* Wt; int K, N, bx, by;
    if (b < 192)      { W = Wqkv; Wt = WqkvT; K = 256;  N = 768;  bx = b & 7;          by = b >> 3; }
    else if (b < 256) { W = Wo;   Wt = WoT;   K = 256;  N = 256;  bx = (b - 192) & 7;  by = (b - 192) >> 3; }
    else if (b < 512) { W = Wi;   Wt = WiT;   K = 256;  N = 1024; bx = (b - 256) & 7;  by = (b - 256) >> 3; }
    else              { W = Wo2;  Wt = Wo2T;  K = 1024; N = 256;  bx = (b - 512) & 31; by = (b - 512) >> 5; }
    const int k0 = bx * 32, n0 = by * 32;
    #pragma unroll
    for (int p = 0; p < 4; ++p) {
        int idx = t + p * 256, r = idx >> 5, c = idx & 31;
        tile[r][c] = W[(size_t)(k0 + r) * N + n0 + c];
    }
    __syncthreads();
    #pragma unroll
    for (int p = 0; p < 4; ++p) {
        int idx = t + p * 256, r = idx >> 5, c = idx & 31;
        Wt[(size_t)(n0 + r) * K + k0 + c] = f2bf(tile[c][r]);
    }
}

// ---------------------------------------------------------------------------
// gemm128<K,N,EPI>: C = A @ Bt^T.  128x128 tile, BK=64, single-buffered,
// XCD row-band swizzle (R2-verified; tiles HAVE cross-wave reuse -> keep
// cooperative staging + barriers).
// ---------------------------------------------------------------------------
template <int K, int N, int EPI>
__global__ __launch_bounds__(256) void gemm128(const unsigned short* __restrict__ A,
                                               const unsigned short* __restrict__ Bt,
                                               unsigned short* __restrict__ C) {
    __shared__ unsigned short As[128 * 64];
    __shared__ unsigned short Bs[128 * 64];
    constexpr int NCOL = N / 128;
    const int b = blockIdx.x;
    const int idx = b >> 3;
    const int r0 = ((b & 7) * 16 + idx / NCOL) * 128;
    const int c0 = (idx % NCOL) * 128;
    const int t = threadIdx.x;
    const int wv = t >> 6, lane = t & 63, q = lane >> 4, l16 = lane & 15;
    const int wr = (wv >> 1) * 64, wc = (wv & 1) * 64;
    f32x4 acc[4][4] = {};

    for (int k0 = 0; k0 < K; k0 += 64) {
        __syncthreads();
        stage<128>(A,  (size_t)r0, K, k0, As, wv, lane);
        stage<128>(Bt, (size_t)c0, K, k0, Bs, wv, lane);
        __builtin_amdgcn_s_waitcnt(0);
        __syncthreads();
        #pragma unroll
        for (int kk2 = 0; kk2 < 2; ++kk2) {
            s16x8 af[4], bfr[4];
            #pragma unroll
            for (int mf = 0; mf < 4; ++mf)
                af[mf] = fragld(As, wr + mf * 16 + l16, kk2 * 4 + q);
            #pragma unroll
            for (int nf = 0; nf < 4; ++nf)
                bfr[nf] = fragld(Bs, wc + nf * 16 + l16, kk2 * 4 + q);
            #pragma unroll
            for (int mf = 0; mf < 4; ++mf)
                #pragma unroll
                for (int nf = 0; nf < 4; ++nf)
                    acc[mf][nf] = __builtin_amdgcn_mfma_f32_16x16x32_bf16(af[mf], bfr[nf], acc[mf][nf], 0, 0, 0);
        }
    }

    #pragma unroll
    for (int mf = 0; mf < 4; ++mf)
        #pragma unroll
        for (int nf = 0; nf < 4; ++nf) {
            const int cg = c0 + wc + nf * 16 + l16;
            #pragma unroll
            for (int r = 0; r < 4; ++r) {
                const int rg = r0 + wr + mf * 16 + q * 4 + r;
                float v = acc[mf][nf][r];
                if (EPI == 1) v = 0.5f * v * (1.f + fast_erf(v * 0.70710678118654752f));
                C[(size_t)rg * N + cg] = f2bf(v);
            }
        }
}

// ---------------------------------------------------------------------------
// ffn_ln: out = LN( gelu(pre @ WiT^T) @ Wo2T^T + pre ), fp32 out.
// FUSED FFN with WAVE-PRIVATE B staging: wave wv consumes only the B rows it
// stages, so each wave stages its own 8KB segment via async global_load_lds
// and waits on its OWN vmcnt — no block-wide drain, no per-round barriers.
// Waves slip freely: one wave's drain overlaps the others' MFMAs (m114).
// Barriers only at the Pbuf cross-wave handoff (9/block vs 65 in R6).
// LDS unchanged: Apre 16K + Bs 32K (4x8K segs) + Pbuf 16K -> 2 blocks/CU.
// ---------------------------------------------------------------------------
__global__ __launch_bounds__(256) void ffn_ln(const unsigned short* __restrict__ preb,
                                              const unsigned short* __restrict__ WiT,
                                              const unsigned short* __restrict__ Wo2T,
                                              const float* __restrict__ gamma,
                                              const float* __restrict__ beta,
                                              float* __restrict__ out) {
    __shared__ unsigned short Apre[8192];          // 16 KB: 4 fragld k-chunk tiles
    __shared__ unsigned short Bs[16384];           // 32 KB: 4 wave-private 8KB segs
    __shared__ unsigned short Pbuf[8192];          // 16 KB: inter chunk, 4 k-sub tiles
    __shared__ float2 partial[4][32];
    __shared__ float2 stats[32];
    const int t = threadIdx.x, r0 = blockIdx.x * 32;
    const int wv = t >> 6, lane = t & 63, q = lane >> 4, l16 = lane & 15;
    const int wc = wv * 64;
    unsigned short* Bseg = Bs + wv * 4096;
    f32x4 acc2[2][4] = {};

    // stage A (preb rows, full K=256) once — cooperative, one barrier
    #pragma unroll
    for (int kc = 0; kc < 4; ++kc)
        stage<32>(preb, (size_t)r0, 256, kc * 64, Apre + kc * 2048, wv, lane);
    __builtin_amdgcn_s_waitcnt(0);
    __syncthreads();

    for (int nc = 0; nc < 4; ++nc) {
        // ---- GEMM1: inter chunk [32 x 256], wave-private B, barrier-free ----
        f32x4 acc1[2][4] = {};
        #pragma unroll
        for (int k0 = 0; k0 < 256; k0 += 64) {
            WAVE_LGKM0();                              // own ds_reads of Bseg done
            stage_wp(WiT, (size_t)(nc * 256 + wc), 256, k0, Bseg, lane);
            WAVE_VM0();                                // own 8 loads landed
            const unsigned short* Ak = Apre + (k0 >> 6) * 2048;
            #pragma unroll
            for (int kk2 = 0; kk2 < 2; ++kk2) {
                s16x8 af[2], bv[4];
                #pragma unroll
                for (int mf = 0; mf < 2; ++mf)
                    af[mf] = fragld(Ak, mf * 16 + l16, kk2 * 4 + q);
                #pragma unroll
                for (int nf = 0; nf < 4; ++nf)
                    bv[nf] = fragld(Bseg, nf * 16 + l16, kk2 * 4 + q);
                #pragma unroll
                for (int mf = 0; mf < 2; ++mf)
                    #pragma unroll
                    for (int nf = 0; nf < 4; ++nf)
                        acc1[mf][nf] = __builtin_amdgcn_mfma_f32_16x16x32_bf16(af[mf], bv[nf], acc1[mf][nf], 0, 0, 0);
            }
        }

        // ---- gelu -> Pbuf (fragld layout; wave wv owns tile wv) ----
        // prev GEMM2's Pbuf reads done: barrier at end of prev nc iteration
        #pragma unroll
        for (int mf = 0; mf < 2; ++mf)
            #pragma unroll
            for (int nf = 0; nf < 4; ++nf)
                #pragma unroll
                for (int r = 0; r < 4; ++r) {
                    float v = acc1[mf][nf][r];
                    v = 0.5f * v * (1.f + fast_erf(v * 0.70710678118654752f));
                    const int i = mf * 16 + q * 4 + r;          // row 0..31
                    const int colc = wc + nf * 16 + l16;        // col in chunk 0..255
                    const int c8 = (colc >> 3) & 7;
                    Pbuf[wv * 2048 + i * 64 + ((c8 ^ (i & 7)) << 3) + (colc & 7)] = f2bf(v);
                }
        __syncthreads();   // Pbuf visible to all waves

        // ---- GEMM2: acc2 += inter_chunk @ Wo2T k-slice, wave-private B ----
        #pragma unroll
        for (int ks = 0; ks < 256; ks += 64) {
            WAVE_LGKM0();
            stage_wp(Wo2T, (size_t)wc, IDIM, nc * 256 + ks, Bseg, lane);
            WAVE_VM0();
            const unsigned short* Pk = Pbuf + (ks >> 6) * 2048;
            #pragma unroll
            for (int kk2 = 0; kk2 < 2; ++kk2) {
                s16x8 af[2], bv[4];
                #pragma unroll
                for (int mf = 0; mf < 2; ++mf)
                    af[mf] = fragld(Pk, mf * 16 + l16, kk2 * 4 + q);
                #pragma unroll
                for (int nf = 0; nf < 4; ++nf)
                    bv[nf] = fragld(Bseg, nf * 16 + l16, kk2 * 4 + q);
                #pragma unroll
                for (int mf = 0; mf < 2; ++mf)
                    #pragma unroll
                    for (int nf = 0; nf < 4; ++nf)
                        acc2[mf][nf] = __builtin_amdgcn_mfma_f32_16x16x32_bf16(af[mf], bv[nf], acc2[mf][nf], 0, 0, 0);
            }
        }
        __syncthreads();   // Pbuf reads done before next nc's gelu overwrites
    }

    // ---- + residual (from Apre LDS, not global) ----
    #pragma unroll
    for (int mf = 0; mf < 2; ++mf)
        #pragma unroll
        for (int nf = 0; nf < 4; ++nf) {
            const int cg = wc + nf * 16 + l16;
            const int kb = cg >> 6, c8 = (cg >> 3) & 7, e = cg & 7;
            #pragma unroll
            for (int r = 0; r < 4; ++r) {
                const int i = mf * 16 + q * 4 + r;
                acc2[mf][nf][r] += bf2f(Apre[kb * 2048 + i * 64 + ((c8 ^ (i & 7)) << 3) + e]);
            }
        }

    // ---- fused row LN ----
    #pragma unroll
    for (int mf = 0; mf < 2; ++mf) {
        float s[4] = {0.f, 0.f, 0.f, 0.f}, ss[4] = {0.f, 0.f, 0.f, 0.f};
        #pragma unroll
        for (int nf = 0; nf < 4; ++nf)
            #pragma unroll
            for (int r = 0; r < 4; ++r) {
                float v = acc2[mf][nf][r];
                s[r] += v; ss[r] += v * v;
            }
        #pragma unroll
        for (int off = 1; off < 16; off <<= 1)
            #pragma unroll
            for (int r = 0; r < 4; ++r) {
                s[r]  += __shfl_xor(s[r],  off);
                ss[r] += __shfl_xor(ss[r], off);
            }
        if (l16 == 0)
            #pragma unroll
            for (int r = 0; r < 4; ++r)
                partial[wv][mf * 16 + q * 4 + r] = make_float2(s[r], ss[r]);
    }
    __syncthreads();
    if (t < 32) {
        float s = 0.f, ss = 0.f;
        #pragma unroll
        for (int w = 0; w < 4; ++w) { s += partial[w][t].x; ss += partial[w][t].y; }
        float mu  = s * (1.f / 256.f);
        float var = ss * (1.f / 256.f) - mu * mu;
        stats[t] = make_float2(mu, rsqrtf(var + LN_EPS));
    }
    __syncthreads();

    #pragma unroll
    for (int mf = 0; mf < 2; ++mf)
        #pragma unroll
        for (int nf = 0; nf < 4; ++nf) {
            const int cg = wc + nf * 16 + l16;
            const float g = gamma[cg], b = beta[cg];
            #pragma unroll
            for (int r = 0; r < 4; ++r) {
                const int rl = mf * 16 + q * 4 + r;
                const float2 st = stats[rl];
                out[(size_t)(r0 + rl) * NH + cg] = (acc2[mf][nf][r] - st.x) * st.y * g + b;
            }
        }
}

// ---------------------------------------------------------------------------
// FUSED attention + W_o GEMM + LN1 — MFMA phase A (R5-verified).
// Phase B: WAVE-PRIVATE WoT staging, barrier-free K-loop (same mechanism as
// ffn_ln).  Bs (32KB, 4 wave segs) overlays Vt+Ps; at overlays Ks.
// ---------------------------------------------------------------------------
__global__ __launch_bounds__(256) void attln(const unsigned short* __restrict__ qkv,
                                             const unsigned short* __restrict__ WoT,
                                             const float* __restrict__ X,
                                             const float* __restrict__ gamma,
                                             const float* __restrict__ beta,
                                             unsigned short* __restrict__ preb) {
    __shared__ unsigned short smem[25216];
    unsigned short* Ks = smem;                 // [0, 8192): h*1024 + j*32 + c*8
    unsigned short* Vt = smem + 8192;          // [8192,16384): h*1024 + d*32 + swz
    unsigned short* Ps = smem + 16384;         // [16384,24576): h*1024 + row*32 + swz
    unsigned short* at = smem;                 // phase B A-tile (overlays Ks)
    unsigned short* Bs = smem + 8192;          // phase B: 4 wave-private 8KB segs
    float2* partial = (float2*)(smem + 24576);
    float2* stats   = (float2*)(smem + 24576 + 512);

    const int g = blockIdx.x, t = threadIdx.x;
    const int wv = t >> 6, lane = t & 63, q = lane >> 4, l16 = lane & 15;
    const unsigned short* src = qkv + (size_t)g * 32 * THREE_NH;

    // ---- Q fragments direct from global ----
    s16x8 qf[2][2];
    #pragma unroll
    for (int hh = 0; hh < 2; ++hh)
        #pragma unroll
        for (int mf = 0; mf < 2; ++mf)
            qf[hh][mf] = *(const s16x8*)&src[(size_t)(mf * 16 + l16) * THREE_NH +
                                             (wv * 2 + hh) * 96 + q * 8];

    // ---- V 16B chunks to regs ----
    s16x8 vld[4];
    int vh[4], vj[4], vdc[4];
    #pragma unroll
    for (int i = 0; i < 4; ++i) {
        int cid = i * 256 + t;
        vh[i] = cid >> 7; int rem = cid & 127; vj[i] = rem >> 2; vdc[i] = rem & 3;
        vld[i] = *(const s16x8*)&src[(size_t)vj[i] * THREE_NH + vh[i] * 96 + 64 + vdc[i] * 8];
    }

    // ---- K async global->LDS ----
    #pragma unroll
    for (int i = 0; i < 4; ++i) {
        int ck = (wv * 4 + i) * 64 + lane;
        int h = ck >> 7, j = (ck >> 2) & 31, c = ck & 3;
        gl2lds16(src + (size_t)j * THREE_NH + h * 96 + 32 + c * 8, Ks + (wv * 4 + i) * 512);
    }

    // ---- Vt scatter: Vt[h][d][j], chunk slot (j>>3) ^ ((d>>2)&3) ----
    #pragma unroll
    for (int i = 0; i < 4; ++i)
        #pragma unroll
        for (int e = 0; e < 8; ++e) {
            int d = vdc[i] * 8 + e;
            Vt[vh[i] * 1024 + d * 32 + ((((vj[i] >> 3) ^ ((d >> 2) & 3))) << 3) + (vj[i] & 7)] =
                (unsigned short)vld[i][e];
        }

    __builtin_amdgcn_s_waitcnt(0);
    __syncthreads();

    // ---- scores: S[h] = Q @ K^T ----
    f32x4 sacc[2][2][2] = {};
    #pragma unroll
    for (int hh = 0; hh < 2; ++hh) {
        const int h = wv * 2 + hh;
        #pragma unroll
        for (int nf = 0; nf < 2; ++nf) {
            s16x8 kf = *(const s16x8*)&Ks[h * 1024 + (nf * 16 + l16) * 32 + q * 8];
            #pragma unroll
            for (int mf = 0; mf < 2; ++mf)
                sacc[hh][mf][nf] = __builtin_amdgcn_mfma_f32_16x16x32_bf16(
                    qf[hh][mf], kf, sacc[hh][mf][nf], 0, 0, 0);
        }
    }

    // ---- softmax (C-layout rows), deferred denominator ----
    float inv[2][2][4];
    #pragma unroll
    for (int hh = 0; hh < 2; ++hh) {
        const int h = wv * 2 + hh;
        #pragma unroll
        for (int mf = 0; mf < 2; ++mf)
            #pragma unroll
            for (int r = 0; r < 4; ++r) {
                float a0 = sacc[hh][mf][0][r], a1 = sacc[hh][mf][1][r];
                float m = fmaxf(a0, a1);
                m = fmaxf(m, __shfl_xor(m, 1));
                m = fmaxf(m, __shfl_xor(m, 2));
                m = fmaxf(m, __shfl_xor(m, 4));
                m = fmaxf(m, __shfl_xor(m, 8));
                float e0 = __expf((a0 - m) * SCL);
                float e1 = __expf((a1 - m) * SCL);
                float sm = e0 + e1;
                sm += __shfl_xor(sm, 1);
                sm += __shfl_xor(sm, 2);
                sm += __shfl_xor(sm, 4);
                sm += __shfl_xor(sm, 8);
                inv[hh][mf][r] = 1.f / sm;
                const int row = mf * 16 + q * 4 + r;
                const int base = h * 1024 + row * 32 + (l16 & 7);
                Ps[base + ((((l16 >> 3) ^ q)) << 3)]       = f2bf(e0);
                Ps[base + ((((2 + (l16 >> 3)) ^ q)) << 3)] = f2bf(e1);
            }
    }

    // ---- PV ----
    f32x4 oacc[2][2][2] = {};
    #pragma unroll
    for (int hh = 0; hh < 2; ++hh) {
        const int h = wv * 2 + hh;
        const int sw = (l16 >> 2) & 3;
        s16x8 pa[2], vb[2];
        #pragma unroll
        for (int mf = 0; mf < 2; ++mf)
            pa[mf] = *(const s16x8*)&Ps[h * 1024 + (mf * 16 + l16) * 32 + ((q ^ sw) << 3)];
        #pragma unroll
        for (int nf = 0; nf < 2; ++nf)
            vb[nf] = *(const s16x8*)&Vt[h * 1024 + (nf * 16 + l16) * 32 + ((q ^ sw) << 3)];
        #pragma unroll
        for (int mf = 0; mf < 2; ++mf)
            #pragma unroll
            for (int nf = 0; nf < 2; ++nf)
                oacc[hh][mf][nf] = __builtin_amdgcn_mfma_f32_16x16x32_bf16(
                    pa[mf], vb[nf], oacc[hh][mf][nf], 0, 0, 0);
    }
    __syncthreads();   // all Ks/Vt/Ps reads done before at/Bs overwrite

    // ---- bridge: O * inv -> at (fragld layout) ----
    #pragma unroll
    for (int hh = 0; hh < 2; ++hh)
        #pragma unroll
        for (int mf = 0; mf < 2; ++mf)
            #pragma unroll
            for (int nf = 0; nf < 2; ++nf)
                #pragma unroll
                for (int r = 0; r < 4; ++r) {
                    float val = oacc[hh][mf][nf][r] * inv[hh][mf][r];
                    const int i = mf * 16 + q * 4 + r;
                    const int col = (wv * 2 + hh) * 32 + nf * 16 + l16;
                    const int kb = col >> 6, c = (col >> 3) & 7;
                    at[kb * 2048 + i * 64 + ((c ^ (i & 7)) << 3) + (col & 7)] = f2bf(val);
                }
    __syncthreads();   // at visible to all waves

    // ---- phase B: pre = LN(at @ WoT^T + X), wave-private B staging ----
    const int wc = wv * 64;
    const int r0 = g * 32;
    unsigned short* Bseg = Bs + wv * 4096;
    f32x4 acc[2][4] = {};

    #pragma unroll
    for (int kc = 0; kc < 4; ++kc) {
        WAVE_LGKM0();
        stage_wp(WoT, (size_t)wc, 256, kc * 64, Bseg, lane);
        WAVE_VM0();
        const unsigned short* atk = at + kc * 2048;
        #pragma unroll
        for (int kk2 = 0; kk2 < 2; ++kk2) {
            s16x8 af[2], bv[4];
            #pragma unroll
            for (int mf = 0; mf < 2; ++mf)
                af[mf] = fragld(atk, mf * 16 + l16, kk2 * 4 + q);
            #pragma unroll
            for (int nf = 0; nf < 4; ++nf)
                bv[nf] = fragld(Bseg, nf * 16 + l16, kk2 * 4 + q);
            #pragma unroll
            for (int mf = 0; mf < 2; ++mf)
                #pragma unroll
                for (int nf = 0; nf < 4; ++nf)
                    acc[mf][nf] = __builtin_amdgcn_mfma_f32_16x16x32_bf16(af[mf], bv[nf], acc[mf][nf], 0, 0, 0);
        }
    }

    #pragma unroll
    for (int mf = 0; mf < 2; ++mf)
        #pragma unroll
        for (int nf = 0; nf < 4; ++nf) {
            const int cg = wc + nf * 16 + l16;
            #pragma unroll
            for (int r = 0; r < 4; ++r)
                acc[mf][nf][r] += X[(size_t)(r0 + mf * 16 + q * 4 + r) * NH + cg];
        }

    #pragma unroll
    for (int mf = 0; mf < 2; ++mf) {
        float sp[4] = {0.f, 0.f, 0.f, 0.f}, ssp[4] = {0.f, 0.f, 0.f, 0.f};
        #pragma unroll
        for (int nf = 0; nf < 4; ++nf)
            #pragma unroll
            for (int r = 0; r < 4; ++r) {
                float v = acc[mf][nf][r];
                sp[r] += v; ssp[r] += v * v;
            }
        #pragma unroll
        for (int off = 1; off < 16; off <<= 1)
            #pragma unroll
            for (int r = 0; r < 4; ++r) {
                sp[r]  += __shfl_xor(sp[r],  off);
                ssp[r] += __shfl_xor(ssp[r], off);
            }
        if (l16 == 0)
            #pragma unroll
            for (int r = 0; r < 4; ++r)
                partial[wv * 32 + mf * 16 + q * 4 + r] = make_float2(sp[r], ssp[r]);
    }
    __syncthreads();
    if (t < 32) {
        float sv = 0.f, ssv = 0.f;
        #pragma unroll
        for (int w = 0; w < 4; ++w) { sv += partial[w * 32 + t].x; ssv += partial[w * 32 + t].y; }
        float mu  = sv * (1.f / 256.f);
        float var = ssv * (1.f / 256.f) - mu * mu;
        stats[t] = make_float2(mu, rsqrtf(var + LN_EPS));
    }
    __syncthreads();

    #pragma unroll
    for (int mf = 0; mf < 2; ++mf)
        #pragma unroll
        for (int nf = 0; nf < 4; ++nf) {
            const int cg = wc + nf * 16 + l16;
            const float gm = gamma[cg], bt = beta[cg];
            #pragma unroll
            for (int r = 0; r < 4; ++r) {
                const int rl = mf * 16 + q * 4 + r;
                const float2 st = stats[rl];
                float v = (acc[mf][nf][r] - st.x) * st.y * gm + bt;
                preb[(size_t)(r0 + rl) * NH + cg] = f2bf(v);
            }
        }
}

// ---------------------------------------------------------------------------
extern "C" void kernel_launch(void* const* d_in, const int* in_sizes, int n_in,
                              void* d_out, int out_size, void* d_ws, size_t ws_size,
                              hipStream_t stream) {
    const float* X      = (const float*)d_in[0];
    const float* W_qkv  = (const float*)d_in[2];
    const float* W_o    = (const float*)d_in[3];
    const float* ln1_g  = (const float*)d_in[4];
    const float* ln1_b  = (const float*)d_in[5];
    const float* W_i    = (const float*)d_in[6];
    const float* W_out2 = (const float*)d_in[7];
    const float* ln2_g  = (const float*)d_in[8];
    const float* ln2_b  = (const float*)d_in[9];
    float* out = (float*)d_out;

    char* ws = (char*)d_ws;
    unsigned short* Xbf   = (unsigned short*)(ws);                 //  8.0 MB
    unsigned short* qkvb  = (unsigned short*)(ws + 8388608);       // 25.2 MB
    unsigned short* preb  = (unsigned short*)(ws + 58720256);      //  8.0 MB
    unsigned short* WqkvT = (unsigned short*)(ws + 67108864);
    unsigned short* WoT   = (unsigned short*)(ws + 67502080);
    unsigned short* WiT   = (unsigned short*)(ws + 67633152);
    unsigned short* Wo2T  = (unsigned short*)(ws + 68157440);

    dim3 blk(256);
    hipLaunchKernelGGL(prep, dim3(768 + V * D / 4 / 256), blk, 0, stream,
                       X, Xbf, W_qkv, W_o, W_i, W_out2, WqkvT, WoT, WiT, Wo2T);

    hipLaunchKernelGGL((gemm128<D, THREE_NH, 0>), dim3(V / 128 * (THREE_NH / 128)), blk, 0, stream,
                       Xbf, WqkvT, qkvb);
    hipLaunchKernelGGL(attln, dim3(V / 32), blk, 0, stream,
                       qkvb, WoT, X, ln1_g, ln1_b, preb);
    hipLaunchKernelGGL(ffn_ln, dim3(V / 32), blk, 0, stream,
                       preb, WiT, Wo2T, ln2_g, ln2_b, out);
}